// Round 3
// baseline (197.771 us; speedup 1.0000x reference)
//
#include <hip/hip_runtime.h>

// VQ-VAE vector quantize + losses, MI355X.
// T=8192 rows, N_E=16384 codes, D=32.
// R18: R17 post-mortem — duration identical to R15 at 2x grid because
//      occupancy stayed ~16 waves/CU: reported VGPR=48 is arch-only; the
//      unified (arch+AGPR) footprint of the 32-row/wave version (~72-96
//      live) lands in the 65..128 band -> 4 waves/SIMD cap, plus accvgpr
//      shuffle traffic inflating VALUBusy to 66%. Fix: shrink the real
//      footprint, don't fight the allocator:
//      - pass1/pass2 restructured to 16 rows(codes)/wave: half the state
//        (m1/m2/Zs/accP/accE x4), one A-frag pair, one accumulator, and
//        no register double-buffer (8 waves/SIMD TLP covers L2 latency).
//        Live set ~46-54 -> fits the <=64-reg / 8-wave band; now
//        __launch_bounds__(256,8) is safe (R16's spill was the 80+-live
//        version forced into 64).
//      - grids stay 2048 blocks = 8 blocks/CU (pass1 128x16, pass2 256x8).
//      - NS1 back to 16 (fewer partials), RS2=8.
//      Tripwire: pass1 WRITE_SIZE must stay ~2.5MB (scratch = failure).

#define N_E 16384
#define ED 32
#define T 8192
#define NS1 16      // pass-1 code splits (1024 codes each)
#define RS2 8       // pass-2 row splits  (1024 rows each)
#define SKIPM -36.0f

#define K2 288.53900817779268f    // 200 * log2(e)
#define NS2F -144.26950408889634f // -100 * log2(e)
#define LN2 0.6931471805599453f

typedef __attribute__((ext_vector_type(8))) short s16x8;
typedef __attribute__((ext_vector_type(4))) float f32x4;

__device__ __forceinline__ float fexp2(float x) { return __builtin_amdgcn_exp2f(x); }
__device__ __forceinline__ float flog2(float x) { return __builtin_amdgcn_logf(x); }
__device__ __forceinline__ float fmed3(float a, float b, float c) {
  return __builtin_amdgcn_fmed3f(a, b, c);
}

__device__ __forceinline__ unsigned short f2bf(float x) {
  unsigned u = __float_as_uint(x);
  unsigned r = (u + 0x7FFFu + ((u >> 16) & 1u)) >> 16;
  return (unsigned short)r;
}
__device__ __forceinline__ float bf2f(unsigned short h) {
  return __uint_as_float(((unsigned)h) << 16);
}

// exact fp32 dot of a streamed row with 8 resident float4s (by value)
__device__ __forceinline__ float dot32x(const float* __restrict__ p,
    float4 z0, float4 z1, float4 z2, float4 z3,
    float4 z4, float4 z5, float4 z6, float4 z7) {
  const float4* e = (const float4*)p;
  float a0 = 0.f, a1 = 0.f, a2 = 0.f, a3 = 0.f; float4 q;
  q = e[0]; a0 = fmaf(q.x, z0.x, a0); a0 = fmaf(q.y, z0.y, a0);
            a0 = fmaf(q.z, z0.z, a0); a0 = fmaf(q.w, z0.w, a0);
  q = e[1]; a1 = fmaf(q.x, z1.x, a1); a1 = fmaf(q.y, z1.y, a1);
            a1 = fmaf(q.z, z1.z, a1); a1 = fmaf(q.w, z1.w, a1);
  q = e[2]; a2 = fmaf(q.x, z2.x, a2); a2 = fmaf(q.y, z2.y, a2);
            a2 = fmaf(q.z, z2.z, a2); a2 = fmaf(q.w, z2.w, a2);
  q = e[3]; a3 = fmaf(q.x, z3.x, a3); a3 = fmaf(q.y, z3.y, a3);
            a3 = fmaf(q.z, z3.z, a3); a3 = fmaf(q.w, z3.w, a3);
  q = e[4]; a0 = fmaf(q.x, z4.x, a0); a0 = fmaf(q.y, z4.y, a0);
            a0 = fmaf(q.z, z4.z, a0); a0 = fmaf(q.w, z4.w, a0);
  q = e[5]; a1 = fmaf(q.x, z5.x, a1); a1 = fmaf(q.y, z5.y, a1);
            a1 = fmaf(q.z, z5.z, a1); a1 = fmaf(q.w, z5.w, a1);
  q = e[6]; a2 = fmaf(q.x, z6.x, a2); a2 = fmaf(q.y, z6.y, a2);
            a2 = fmaf(q.z, z6.z, a2); a2 = fmaf(q.w, z6.w, a2);
  q = e[7]; a3 = fmaf(q.x, z7.x, a3); a3 = fmaf(q.y, z7.y, a3);
            a3 = fmaf(q.z, z7.z, a3); a3 = fmaf(q.w, z7.w, a3);
  return (a0 + a1) + (a2 + a3);
}

// split 8 floats (scaled by sc) of row `row`, group g into hi/lo bf16 frags,
// stored TILE-MAJOR: dst[tile*128 + g*16 + c] (hi), +64 (lo); s16x8 units.
__device__ __forceinline__ void split_store_t(short* __restrict__ base,
    int row, int g, float4 va, float4 vb, float sc) {
  float f[8] = { va.x * sc, va.y * sc, va.z * sc, va.w * sc,
                 vb.x * sc, vb.y * sc, vb.z * sc, vb.w * sc };
  s16x8 H, L;
#pragma unroll
  for (int e = 0; e < 8; ++e) {
    unsigned short h = f2bf(f[e]);
    H[e] = (short)h;
    L[e] = (short)f2bf(f[e] - bf2f(h));
  }
  s16x8* p = (s16x8*)base;
  const int tile = row >> 4, c = row & 15;
  p[tile * 128 + g * 16 + c] = H;
  p[tile * 128 + 64 + g * 16 + c] = L;
}

// --- prep: blocks 0..63 emb rows; 64..95 z transpose; 96..160 zero avg/scal ---
__global__ __launch_bounds__(256) void k_prep(const float* __restrict__ emb,
    const float* __restrict__ z, float* __restrict__ embn,
    float* __restrict__ ses2, float* __restrict__ zf, float* __restrict__ a02,
    short* __restrict__ ehl, short* __restrict__ zhl, float* __restrict__ avg,
    float* __restrict__ scal) {
  if (blockIdx.x < 64) {
    int n = blockIdx.x * 256 + threadIdx.x;
    const float4* r4 = (const float4*)(emb + (size_t)n * ED);
    float4 v[8]; float s = 0.f;
#pragma unroll
    for (int j = 0; j < 8; ++j) {
      v[j] = r4[j];
      s = fmaf(v[j].x, v[j].x, s); s = fmaf(v[j].y, v[j].y, s);
      s = fmaf(v[j].z, v[j].z, s); s = fmaf(v[j].w, v[j].w, s);
    }
    float inv = 1.0f / fmaxf(sqrtf(s), 1e-12f);
    float s2 = 0.f;
    float4* o4 = (float4*)(embn + (size_t)n * ED);
#pragma unroll
    for (int j = 0; j < 8; ++j) {
      float4 w; w.x = v[j].x * inv; w.y = v[j].y * inv;
      w.z = v[j].z * inv; w.w = v[j].w * inv;
      o4[j] = w; v[j] = w;
      s2 = fmaf(w.x, w.x, s2); s2 = fmaf(w.y, w.y, s2);
      s2 = fmaf(w.z, w.z, s2); s2 = fmaf(w.w, w.w, s2);
    }
    ses2[n] = NS2F * s2;               // true value, for the exact refine
#pragma unroll
    for (int g = 0; g < 4; ++g)
      split_store_t(ehl, n, g, v[2 * g], v[2 * g + 1], 1.0f);
  } else if (blockIdx.x < 96) {
    int t = (blockIdx.x - 64) * 256 + threadIdx.x;
    int b = t >> 8, hw = t & 255;
    const float* base = z + (size_t)b * (ED * 256) + hw;
    float4 v[8]; float s = 0.f;
#pragma unroll
    for (int j = 0; j < 8; ++j) {
      float4 w;
      w.x = base[(4 * j + 0) * 256]; w.y = base[(4 * j + 1) * 256];
      w.z = base[(4 * j + 2) * 256]; w.w = base[(4 * j + 3) * 256];
      v[j] = w;
      s = fmaf(w.x, w.x, s); s = fmaf(w.y, w.y, s);
      s = fmaf(w.z, w.z, s); s = fmaf(w.w, w.w, s);
    }
    float inv = 1.0f / fmaxf(sqrtf(s), 1e-12f);
    float s2 = 0.f;
    float4* o4 = (float4*)(zf + (size_t)t * ED);
#pragma unroll
    for (int j = 0; j < 8; ++j) {
      float4 w; w.x = v[j].x * inv; w.y = v[j].y * inv;
      w.z = v[j].z * inv; w.w = v[j].w * inv;
      o4[j] = w; v[j] = w;
      s2 = fmaf(w.x, w.x, s2); s2 = fmaf(w.y, w.y, s2);
      s2 = fmaf(w.z, w.z, s2); s2 = fmaf(w.w, w.w, s2);
    }
    a02[t] = NS2F * s2;
#pragma unroll
    for (int g = 0; g < 4; ++g)
      split_store_t(zhl, t, g, v[2 * g], v[2 * g + 1], K2);
  } else if (blockIdx.x < 160) {
    avg[(blockIdx.x - 96) * 256 + threadIdx.x] = 0.f;
  } else {
    if (threadIdx.x < 4) scal[threadIdx.x] = 0.f;  // [0]=sampE [1]=vq [2]=cnt
  }
}

// --- pass 1: wave owns 16 rows, sweeps a 1024-code split in 16-code tiles.
//     C-bias = a02 + 80 + NS2F (ses2 folded); fb = acc. Top-2 via
//     mantissa-packed keys (tile idx in low 6 bits; med3+max only).
//     Live set ~50 regs -> 8 waves/SIMD; no register prefetch (TLP covers).
__global__ __launch_bounds__(256, 8) void k_pass1(
    const short* __restrict__ ehl, const short* __restrict__ zhl,
    const float* __restrict__ a02, float* __restrict__ pm1,
    float* __restrict__ pm2, float* __restrict__ pZ,
    int* __restrict__ pi1, int* __restrict__ pi2) {
  const int lane = threadIdx.x & 63, wv = threadIdx.x >> 6;
  const int q = lane >> 4, c = lane & 15;
  const int rowbase = blockIdx.x * 64 + wv * 16;
  const int nb0 = blockIdx.y * (N_E / NS1);
  const int NT = (N_E / NS1) / 16;  // 64

  const s16x8* zg = (const s16x8*)zhl;
  const int atile = rowbase >> 4;
  s16x8 ah = zg[atile * 128 + lane], al = zg[atile * 128 + 64 + lane];

  f32x4 bias;
#pragma unroll
  for (int r = 0; r < 4; ++r)
    bias[r] = a02[rowbase + q * 4 + r] + (80.0f + NS2F);

  float m1[4], m2[4], Zs[4];
#pragma unroll
  for (int k = 0; k < 4; ++k) { m1[k] = -1e30f; m2[k] = -1e30f; Zs[k] = 0.f; }

  const s16x8* eg = (const s16x8*)ehl + (size_t)(nb0 >> 4) * 128;

  for (int tile = 0; tile < NT; ++tile) {
    s16x8 bh = eg[lane], bl = eg[64 + lane];
    eg += 128;

    f32x4 acc = __builtin_amdgcn_mfma_f32_16x16x32_bf16(ah, bh, bias, 0, 0, 0);
    acc = __builtin_amdgcn_mfma_f32_16x16x32_bf16(al, bh, acc, 0, 0, 0);
    acc = __builtin_amdgcn_mfma_f32_16x16x32_bf16(ah, bl, acc, 0, 0, 0);

    const unsigned tu = (unsigned)tile;                   // uniform 6-bit idx
#pragma unroll
    for (int r = 0; r < 4; ++r) {
      float fb = acc[r];
      float key = __uint_as_float((__float_as_uint(fb) & 0xFFFFFFC0u) | tu);
      m2[r] = fmed3(key, m1[r], m2[r]);   // 2nd-max of {key,m1,m2}
      m1[r] = fmaxf(m1[r], key);
      Zs[r] += fexp2(fb);
    }
  }

  // decode indices from this lane's own keys (c local), then reduce
  int i1[4], i2[4];
#pragma unroll
  for (int k = 0; k < 4; ++k) {
    i1[k] = nb0 + (int)((__float_as_uint(m1[k]) & 63u) << 4) + c;
    i2[k] = nb0 + (int)((__float_as_uint(m2[k]) & 63u) << 4) + c;
  }

#pragma unroll
  for (int d = 1; d < 16; d <<= 1) {
#pragma unroll
    for (int k = 0; k < 4; ++k) {
      float om1 = __shfl_xor(m1[k], d);
      float om2 = __shfl_xor(m2[k], d);
      float oZ = __shfl_xor(Zs[k], d);
      int oi1 = __shfl_xor(i1[k], d);
      int oi2 = __shfl_xor(i2[k], d);
      bool c1 = om1 > m1[k];
      float lm = c1 ? m1[k] : om1;
      int li = c1 ? i1[k] : oi1;
      float nm1 = c1 ? om1 : m1[k];
      int ni1 = c1 ? oi1 : i1[k];
      bool cb = om2 > m2[k];
      float mm2 = cb ? om2 : m2[k];
      int mi2 = cb ? oi2 : i2[k];
      bool c3 = mm2 > lm;
      m1[k] = nm1; i1[k] = ni1;
      m2[k] = c3 ? mm2 : lm;
      i2[k] = c3 ? mi2 : li;
      Zs[k] += oZ;
    }
  }

#pragma unroll
  for (int k = 0; k < 4; ++k) {
    if (c == k) {
      const int t = rowbase + q * 4 + k;
      const int p = blockIdx.y * T + t;
      pm1[p] = m1[k]; pm2[p] = m2[k]; pZ[p] = Zs[k];
      pi1[p] = i1[k]; pi2[p] = i2[k];
    }
  }
}

// --- zred: per-row Z merge + lse shift, once (pass2 would otherwise
//     recompute it redundantly in 2048 block preambles). ---
__global__ __launch_bounds__(256) void k_zred(const float* __restrict__ pZ,
    const float* __restrict__ a02, float* __restrict__ sc2g) {
  const int t = blockIdx.x * 256 + threadIdx.x;
  float Z = 0.f;
  for (int s = 0; s < NS1; ++s) Z += pZ[s * T + t];
  sc2g[t] = a02[t] - (flog2(Z) - 80.0f);
}

// --- pass 2: 2048 uniform blocks (8/CU); wave owns 16 codes, sweeps a
//     1024-row split. Tile-skip: contribute only if max(fb)+cc > -36
//     (dropped mass < N_E*2^-36 rel). Live set ~48 -> 8 waves/SIMD. ---
__global__ __launch_bounds__(256, 8) void k_pass2(
    const short* __restrict__ ehl, const short* __restrict__ zhl,
    const float* __restrict__ sc2g,
    float* __restrict__ avg, float* __restrict__ scal) {
  const int bid = blockIdx.x;
  const int tid = threadIdx.x;
  __shared__ float red[256];
  __shared__ float sc2[T / RS2];      // 1024

  const int bx = bid & 255, by = bid >> 8;
  const int tb0 = by * (T / RS2);
  for (int i = tid; i < T / RS2; i += 256) sc2[i] = sc2g[tb0 + i];
  __syncthreads();

  const int lane = tid & 63, wv = tid >> 6;
  const int q = lane >> 4, c = lane & 15;
  const int cbase = bx * 64 + wv * 16;
  const int NT = (T / RS2) / 16;     // 64

  const s16x8* eg = (const s16x8*)ehl;
  const int atile = cbase >> 4;
  s16x8 ah = eg[atile * 128 + lane], al = eg[atile * 128 + 64 + lane];

  f32x4 sg;                           // ses2 ~ const (consistent with pass1)
#pragma unroll
  for (int r = 0; r < 4; ++r) sg[r] = NS2F;

  float accP[4], accE[4];
#pragma unroll
  for (int k = 0; k < 4; ++k) { accP[k] = 0.f; accE[k] = 0.f; }

  const s16x8* zt = (const s16x8*)zhl + (size_t)(tb0 >> 4) * 128;

  for (int tile = 0; tile < NT; ++tile) {
    s16x8 bh = zt[lane], bl = zt[64 + lane];
    zt += 128;
    float cc = sc2[tile * 16 + c];

    f32x4 acc = __builtin_amdgcn_mfma_f32_16x16x32_bf16(ah, bh, sg, 0, 0, 0);
    acc = __builtin_amdgcn_mfma_f32_16x16x32_bf16(al, bh, acc, 0, 0, 0);
    acc = __builtin_amdgcn_mfma_f32_16x16x32_bf16(ah, bl, acc, 0, 0, 0);

    // tile-skip: per-lane max over this lane's 4 elements (all share column
    // c -> same cc); wave-uniform branch.
    float m4 = fmaxf(fmaxf(acc[0], acc[1]), fmaxf(acc[2], acc[3]));
    if (__any(m4 + cc > SKIPM)) {
#pragma unroll
      for (int r = 0; r < 4; ++r) {
        float dl = acc[r] + cc;       // fb - lse2 (<=0)
        float p = fexp2(dl);          // underflow -> 0
        accP[r] += p;
        accE[r] = fmaf(p, dl, accE[r]);
      }
    }
  }

  float etot = 0.f;
#pragma unroll
  for (int k = 0; k < 4; ++k) etot += accE[k];

#pragma unroll
  for (int d = 1; d < 16; d <<= 1) {
#pragma unroll
    for (int k = 0; k < 4; ++k) accP[k] += __shfl_xor(accP[k], d);
  }
#pragma unroll
  for (int k = 0; k < 4; ++k) {
    if (c == k) {
      atomicAdd(&avg[cbase + q * 4 + k], accP[k]);
    }
  }
  red[tid] = etot;
  __syncthreads();
  for (int st = 128; st > 0; st >>= 1) {
    if (tid < st) red[tid] += red[tid + st];
    __syncthreads();
  }
  if (tid == 0) atomicAdd(&scal[0], red[0]);
}

// --- merge-final: 32 blocks, thread = row. Top-2 combine (no Z needed),
//     exact fp32 refine, vq sum + straight-through output. Last finished
//     block computes the final scalars (counter on scal[2], 32 fences). ---
__global__ __launch_bounds__(256) void k_mf(
    const float* __restrict__ pm1, const float* __restrict__ pm2,
    const int* __restrict__ pi1, const int* __restrict__ pi2,
    const float* __restrict__ zf, const float* __restrict__ embn,
    const float* __restrict__ ses2, const float* __restrict__ a02,
    float* __restrict__ avg, float* __restrict__ scal, float* __restrict__ out) {
  const int tid = threadIdx.x;
  const int t = blockIdx.x * 256 + tid;
  __shared__ float red[256];
  __shared__ unsigned sord;

  float m1 = -1e30f, m2 = -1e30f;
  int i1 = 0, i2 = 0;
  for (int s = 0; s < NS1; ++s) {
    const int p = s * T + t;
    float sm1 = pm1[p], sm2 = pm2[p];
    int si1 = pi1[p], si2 = pi2[p];
    bool c1 = sm1 > m1;
    float lm = c1 ? m1 : sm1;
    int li = c1 ? i1 : si1;
    float nm1 = c1 ? sm1 : m1;
    int ni1 = c1 ? si1 : i1;
    bool cb = sm2 > m2;
    float mm2 = cb ? sm2 : m2;
    int mi2 = cb ? si2 : i2;
    bool c3 = mm2 > lm;
    m1 = nm1; i1 = ni1;
    m2 = c3 ? mm2 : lm;
    i2 = c3 ? mi2 : li;
  }
  const float a02t = a02[t];

  const float4* zr4 = (const float4*)(zf + (size_t)t * ED);
  float4 z0 = zr4[0], z1 = zr4[1], z2 = zr4[2], z3 = zr4[3];
  float4 z4 = zr4[4], z5 = zr4[5], z6 = zr4[6], z7 = zr4[7];
  float d1 = dot32x(embn + (size_t)i1 * ED, z0, z1, z2, z3, z4, z5, z6, z7);
  float d2 = dot32x(embn + (size_t)i2 * ED, z0, z1, z2, z3, z4, z5, z6, z7);
  float fb1 = fmaf(K2, d1, a02t + ses2[i1]);   // true ses2: exact rule
  float fb2 = fmaf(K2, d2, a02t + ses2[i2]);
  int bi = (fb2 > fb1 || (fb2 == fb1 && i2 < i1)) ? i2 : i1;

  const int b = t >> 8, hw = t & 255;
  float* ob = out + (size_t)b * (ED * 256) + hw;
  float ss = 0.f;
  const float4* e4 = (const float4*)(embn + (size_t)bi * ED);
#pragma unroll
  for (int j = 0; j < 8; ++j) {
    float4 qv = e4[j];
    float4 zv = (j == 0) ? z0 : (j == 1) ? z1 : (j == 2) ? z2 : (j == 3) ? z3
              : (j == 4) ? z4 : (j == 5) ? z5 : (j == 6) ? z6 : z7;
    float df;
    df = qv.x - zv.x; ss = fmaf(df, df, ss); ob[(4 * j + 0) * 256] = zv.x + (qv.x - zv.x);
    df = qv.y - zv.y; ss = fmaf(df, df, ss); ob[(4 * j + 1) * 256] = zv.y + (qv.y - zv.y);
    df = qv.z - zv.z; ss = fmaf(df, df, ss); ob[(4 * j + 2) * 256] = zv.z + (qv.z - zv.z);
    df = qv.w - zv.w; ss = fmaf(df, df, ss); ob[(4 * j + 3) * 256] = zv.w + (qv.w - zv.w);
  }
  red[tid] = ss;
  __syncthreads();
  for (int st = 128; st > 0; st >>= 1) {
    if (tid < st) red[tid] += red[tid + st];
    __syncthreads();
  }
  if (tid == 0) atomicAdd(&scal[1], red[0]);

  // last-block final (avg/scal[0] were completed by the previous kernel)
  __threadfence();
  __syncthreads();
  if (tid == 0) sord = atomicAdd((unsigned*)&scal[2], 1u);
  __syncthreads();
  if (sord == 31) {
    float s = 0.f;
    for (int i = tid; i < N_E; i += 256) {
      float a = avg[i] * (1.0f / T);
      s += a * (flog2(a + 1e-5f) * LN2);
    }
    red[tid] = s;
    __syncthreads();
    for (int st = 128; st > 0; st >>= 1) {
      if (tid < st) red[tid] += red[tid + st];
      __syncthreads();
    }
    if (tid == 0) {
      float avg_entropy = -red[0];
      float se = scal[0];
      float vqs = __hip_atomic_load(&scal[1], __ATOMIC_RELAXED,
                                    __HIP_MEMORY_SCOPE_AGENT);
      float sample_entropy = -(se * LN2) * (1.0f / T);
      float vq = vqs * (1.0f / (T * ED));
      out[T * ED + 0] = vq;
      out[T * ED + 1] = 0.25f * vq;
      out[T * ED + 2] = 0.1f * (sample_entropy - avg_entropy);
    }
  }
}

extern "C" void kernel_launch(void* const* d_in, const int* in_sizes, int n_in,
                              void* d_out, int out_size, void* d_ws, size_t ws_size,
                              hipStream_t stream) {
  const float* z = (const float*)d_in[0];
  const float* emb = (const float*)d_in[1];
  float* out = (float*)d_out;
  float* w = (float*)d_ws;

  float* embn = w;                          // 524288 f
  float* ses2 = embn + 524288;              // 16384
  float* zf   = ses2 + 16384;               // 262144
  float* a02  = zf + 262144;                // 8192
  short* ehl  = (short*)(a02 + 8192);       // 1048576 sh (524288 f)
  short* zhl  = ehl + 1048576;              // 524288 sh  (262144 f)
  float* pm1  = (float*)(zhl + 524288);     // NS1*T = 131072 f
  float* pm2  = pm1 + NS1 * T;              // 131072
  float* pZ   = pm2 + NS1 * T;              // 131072
  int*   pi1  = (int*)(pZ + NS1 * T);       // 131072
  int*   pi2  = pi1 + NS1 * T;              // 131072
  float* avg  = (float*)(pi2 + NS1 * T);    // 16384
  float* scal = avg + 16384;                // 4: sampE, vq, counter, pad
  float* sc2g = scal + 4;                   // 8192

  k_prep<<<161, 256, 0, stream>>>(emb, z, embn, ses2, zf, a02, ehl, zhl,
                                  avg, scal);
  k_pass1<<<dim3(T / 64, NS1), 256, 0, stream>>>(ehl, zhl, a02,
                                                 pm1, pm2, pZ, pi1, pi2);
  k_zred<<<T / 256, 256, 0, stream>>>(pZ, a02, sc2g);
  k_pass2<<<256 * RS2, 256, 0, stream>>>(ehl, zhl, sc2g, avg, scal);
  k_mf<<<32, 256, 0, stream>>>(pm1, pm2, pi1, pi2, zf, embn, ses2, a02,
                               avg, scal, out);
}

// Round 4
// 197.434 us; speedup vs baseline: 1.0017x; 1.0017x over previous
//
#include <hip/hip_runtime.h>

// VQ-VAE vector quantize + losses, MI355X.
// T=8192 rows, N_E=16384 codes, D=32.
// R19: R18 post-mortem — clean regs (VGPR 24, VALUBusy 23.7% = AGPR-shuffle
//      theory confirmed) + 58% occupancy, but dur flat: waves stall ~75%
//      on s_waitcnt; ~1400cyc/tile vs ~75 issue-cyc. R18 removed the
//      register prefetch -> every tile exposes full contended-L2 latency
//      (32 CUs/XCD stream the same 2MB -> 600-1000cyc loaded latency).
//      R19 = R18 + single-tile register prefetch in both sweeps (+16 VGPR,
//      live set ~56 <= 64, still 8 waves/SIMD). Nothing else changed.
//      Tripwire: pass WRITE_SIZE must stay ~2.5MB (growth = spill).

#define N_E 16384
#define ED 32
#define T 8192
#define NS1 16      // pass-1 code splits (1024 codes each)
#define RS2 8       // pass-2 row splits  (1024 rows each)
#define SKIPM -36.0f

#define K2 288.53900817779268f    // 200 * log2(e)
#define NS2F -144.26950408889634f // -100 * log2(e)
#define LN2 0.6931471805599453f

typedef __attribute__((ext_vector_type(8))) short s16x8;
typedef __attribute__((ext_vector_type(4))) float f32x4;

__device__ __forceinline__ float fexp2(float x) { return __builtin_amdgcn_exp2f(x); }
__device__ __forceinline__ float flog2(float x) { return __builtin_amdgcn_logf(x); }
__device__ __forceinline__ float fmed3(float a, float b, float c) {
  return __builtin_amdgcn_fmed3f(a, b, c);
}

__device__ __forceinline__ unsigned short f2bf(float x) {
  unsigned u = __float_as_uint(x);
  unsigned r = (u + 0x7FFFu + ((u >> 16) & 1u)) >> 16;
  return (unsigned short)r;
}
__device__ __forceinline__ float bf2f(unsigned short h) {
  return __uint_as_float(((unsigned)h) << 16);
}

// exact fp32 dot of a streamed row with 8 resident float4s (by value)
__device__ __forceinline__ float dot32x(const float* __restrict__ p,
    float4 z0, float4 z1, float4 z2, float4 z3,
    float4 z4, float4 z5, float4 z6, float4 z7) {
  const float4* e = (const float4*)p;
  float a0 = 0.f, a1 = 0.f, a2 = 0.f, a3 = 0.f; float4 q;
  q = e[0]; a0 = fmaf(q.x, z0.x, a0); a0 = fmaf(q.y, z0.y, a0);
            a0 = fmaf(q.z, z0.z, a0); a0 = fmaf(q.w, z0.w, a0);
  q = e[1]; a1 = fmaf(q.x, z1.x, a1); a1 = fmaf(q.y, z1.y, a1);
            a1 = fmaf(q.z, z1.z, a1); a1 = fmaf(q.w, z1.w, a1);
  q = e[2]; a2 = fmaf(q.x, z2.x, a2); a2 = fmaf(q.y, z2.y, a2);
            a2 = fmaf(q.z, z2.z, a2); a2 = fmaf(q.w, z2.w, a2);
  q = e[3]; a3 = fmaf(q.x, z3.x, a3); a3 = fmaf(q.y, z3.y, a3);
            a3 = fmaf(q.z, z3.z, a3); a3 = fmaf(q.w, z3.w, a3);
  q = e[4]; a0 = fmaf(q.x, z4.x, a0); a0 = fmaf(q.y, z4.y, a0);
            a0 = fmaf(q.z, z4.z, a0); a0 = fmaf(q.w, z4.w, a0);
  q = e[5]; a1 = fmaf(q.x, z5.x, a1); a1 = fmaf(q.y, z5.y, a1);
            a1 = fmaf(q.z, z5.z, a1); a1 = fmaf(q.w, z5.w, a1);
  q = e[6]; a2 = fmaf(q.x, z6.x, a2); a2 = fmaf(q.y, z6.y, a2);
            a2 = fmaf(q.z, z6.z, a2); a2 = fmaf(q.w, z6.w, a2);
  q = e[7]; a3 = fmaf(q.x, z7.x, a3); a3 = fmaf(q.y, z7.y, a3);
            a3 = fmaf(q.z, z7.z, a3); a3 = fmaf(q.w, z7.w, a3);
  return (a0 + a1) + (a2 + a3);
}

// split 8 floats (scaled by sc) of row `row`, group g into hi/lo bf16 frags,
// stored TILE-MAJOR: dst[tile*128 + g*16 + c] (hi), +64 (lo); s16x8 units.
__device__ __forceinline__ void split_store_t(short* __restrict__ base,
    int row, int g, float4 va, float4 vb, float sc) {
  float f[8] = { va.x * sc, va.y * sc, va.z * sc, va.w * sc,
                 vb.x * sc, vb.y * sc, vb.z * sc, vb.w * sc };
  s16x8 H, L;
#pragma unroll
  for (int e = 0; e < 8; ++e) {
    unsigned short h = f2bf(f[e]);
    H[e] = (short)h;
    L[e] = (short)f2bf(f[e] - bf2f(h));
  }
  s16x8* p = (s16x8*)base;
  const int tile = row >> 4, c = row & 15;
  p[tile * 128 + g * 16 + c] = H;
  p[tile * 128 + 64 + g * 16 + c] = L;
}

// --- prep: blocks 0..63 emb rows; 64..95 z transpose; 96..160 zero avg/scal ---
__global__ __launch_bounds__(256) void k_prep(const float* __restrict__ emb,
    const float* __restrict__ z, float* __restrict__ embn,
    float* __restrict__ ses2, float* __restrict__ zf, float* __restrict__ a02,
    short* __restrict__ ehl, short* __restrict__ zhl, float* __restrict__ avg,
    float* __restrict__ scal) {
  if (blockIdx.x < 64) {
    int n = blockIdx.x * 256 + threadIdx.x;
    const float4* r4 = (const float4*)(emb + (size_t)n * ED);
    float4 v[8]; float s = 0.f;
#pragma unroll
    for (int j = 0; j < 8; ++j) {
      v[j] = r4[j];
      s = fmaf(v[j].x, v[j].x, s); s = fmaf(v[j].y, v[j].y, s);
      s = fmaf(v[j].z, v[j].z, s); s = fmaf(v[j].w, v[j].w, s);
    }
    float inv = 1.0f / fmaxf(sqrtf(s), 1e-12f);
    float s2 = 0.f;
    float4* o4 = (float4*)(embn + (size_t)n * ED);
#pragma unroll
    for (int j = 0; j < 8; ++j) {
      float4 w; w.x = v[j].x * inv; w.y = v[j].y * inv;
      w.z = v[j].z * inv; w.w = v[j].w * inv;
      o4[j] = w; v[j] = w;
      s2 = fmaf(w.x, w.x, s2); s2 = fmaf(w.y, w.y, s2);
      s2 = fmaf(w.z, w.z, s2); s2 = fmaf(w.w, w.w, s2);
    }
    ses2[n] = NS2F * s2;               // true value, for the exact refine
#pragma unroll
    for (int g = 0; g < 4; ++g)
      split_store_t(ehl, n, g, v[2 * g], v[2 * g + 1], 1.0f);
  } else if (blockIdx.x < 96) {
    int t = (blockIdx.x - 64) * 256 + threadIdx.x;
    int b = t >> 8, hw = t & 255;
    const float* base = z + (size_t)b * (ED * 256) + hw;
    float4 v[8]; float s = 0.f;
#pragma unroll
    for (int j = 0; j < 8; ++j) {
      float4 w;
      w.x = base[(4 * j + 0) * 256]; w.y = base[(4 * j + 1) * 256];
      w.z = base[(4 * j + 2) * 256]; w.w = base[(4 * j + 3) * 256];
      v[j] = w;
      s = fmaf(w.x, w.x, s); s = fmaf(w.y, w.y, s);
      s = fmaf(w.z, w.z, s); s = fmaf(w.w, w.w, s);
    }
    float inv = 1.0f / fmaxf(sqrtf(s), 1e-12f);
    float s2 = 0.f;
    float4* o4 = (float4*)(zf + (size_t)t * ED);
#pragma unroll
    for (int j = 0; j < 8; ++j) {
      float4 w; w.x = v[j].x * inv; w.y = v[j].y * inv;
      w.z = v[j].z * inv; w.w = v[j].w * inv;
      o4[j] = w; v[j] = w;
      s2 = fmaf(w.x, w.x, s2); s2 = fmaf(w.y, w.y, s2);
      s2 = fmaf(w.z, w.z, s2); s2 = fmaf(w.w, w.w, s2);
    }
    a02[t] = NS2F * s2;
#pragma unroll
    for (int g = 0; g < 4; ++g)
      split_store_t(zhl, t, g, v[2 * g], v[2 * g + 1], K2);
  } else if (blockIdx.x < 160) {
    avg[(blockIdx.x - 96) * 256 + threadIdx.x] = 0.f;
  } else {
    if (threadIdx.x < 4) scal[threadIdx.x] = 0.f;  // [0]=sampE [1]=vq [2]=cnt
  }
}

// --- pass 1: wave owns 16 rows, sweeps a 1024-code split in 16-code tiles.
//     C-bias = a02 + 80 + NS2F (ses2 folded); fb = acc. Top-2 via
//     mantissa-packed keys (tile idx in low 6 bits; med3+max only).
//     Live set ~56 regs (incl. 1-tile prefetch) -> 8 waves/SIMD. ---
__global__ __launch_bounds__(256, 8) void k_pass1(
    const short* __restrict__ ehl, const short* __restrict__ zhl,
    const float* __restrict__ a02, float* __restrict__ pm1,
    float* __restrict__ pm2, float* __restrict__ pZ,
    int* __restrict__ pi1, int* __restrict__ pi2) {
  const int lane = threadIdx.x & 63, wv = threadIdx.x >> 6;
  const int q = lane >> 4, c = lane & 15;
  const int rowbase = blockIdx.x * 64 + wv * 16;
  const int nb0 = blockIdx.y * (N_E / NS1);
  const int NT = (N_E / NS1) / 16;  // 64

  const s16x8* zg = (const s16x8*)zhl;
  const int atile = rowbase >> 4;
  s16x8 ah = zg[atile * 128 + lane], al = zg[atile * 128 + 64 + lane];

  f32x4 bias;
#pragma unroll
  for (int r = 0; r < 4; ++r)
    bias[r] = a02[rowbase + q * 4 + r] + (80.0f + NS2F);

  float m1[4], m2[4], Zs[4];
#pragma unroll
  for (int k = 0; k < 4; ++k) { m1[k] = -1e30f; m2[k] = -1e30f; Zs[k] = 0.f; }

  const s16x8* eg = (const s16x8*)ehl + (size_t)(nb0 >> 4) * 128;
  s16x8 bh = eg[lane], bl = eg[64 + lane];

  for (int tile = 0; tile < NT; ++tile) {
    const int nx = (tile + 1 < NT) ? tile + 1 : tile;     // uniform
    s16x8 nh = eg[nx * 128 + lane], nl = eg[nx * 128 + 64 + lane];  // prefetch

    f32x4 acc = __builtin_amdgcn_mfma_f32_16x16x32_bf16(ah, bh, bias, 0, 0, 0);
    acc = __builtin_amdgcn_mfma_f32_16x16x32_bf16(al, bh, acc, 0, 0, 0);
    acc = __builtin_amdgcn_mfma_f32_16x16x32_bf16(ah, bl, acc, 0, 0, 0);

    const unsigned tu = (unsigned)tile;                   // uniform 6-bit idx
#pragma unroll
    for (int r = 0; r < 4; ++r) {
      float fb = acc[r];
      float key = __uint_as_float((__float_as_uint(fb) & 0xFFFFFFC0u) | tu);
      m2[r] = fmed3(key, m1[r], m2[r]);   // 2nd-max of {key,m1,m2}
      m1[r] = fmaxf(m1[r], key);
      Zs[r] += fexp2(fb);
    }
    bh = nh; bl = nl;
  }

  // decode indices from this lane's own keys (c local), then reduce
  int i1[4], i2[4];
#pragma unroll
  for (int k = 0; k < 4; ++k) {
    i1[k] = nb0 + (int)((__float_as_uint(m1[k]) & 63u) << 4) + c;
    i2[k] = nb0 + (int)((__float_as_uint(m2[k]) & 63u) << 4) + c;
  }

#pragma unroll
  for (int d = 1; d < 16; d <<= 1) {
#pragma unroll
    for (int k = 0; k < 4; ++k) {
      float om1 = __shfl_xor(m1[k], d);
      float om2 = __shfl_xor(m2[k], d);
      float oZ = __shfl_xor(Zs[k], d);
      int oi1 = __shfl_xor(i1[k], d);
      int oi2 = __shfl_xor(i2[k], d);
      bool c1 = om1 > m1[k];
      float lm = c1 ? m1[k] : om1;
      int li = c1 ? i1[k] : oi1;
      float nm1 = c1 ? om1 : m1[k];
      int ni1 = c1 ? oi1 : i1[k];
      bool cb = om2 > m2[k];
      float mm2 = cb ? om2 : m2[k];
      int mi2 = cb ? oi2 : i2[k];
      bool c3 = mm2 > lm;
      m1[k] = nm1; i1[k] = ni1;
      m2[k] = c3 ? mm2 : lm;
      i2[k] = c3 ? mi2 : li;
      Zs[k] += oZ;
    }
  }

#pragma unroll
  for (int k = 0; k < 4; ++k) {
    if (c == k) {
      const int t = rowbase + q * 4 + k;
      const int p = blockIdx.y * T + t;
      pm1[p] = m1[k]; pm2[p] = m2[k]; pZ[p] = Zs[k];
      pi1[p] = i1[k]; pi2[p] = i2[k];
    }
  }
}

// --- zred: per-row Z merge + lse shift, once (pass2 would otherwise
//     recompute it redundantly in 2048 block preambles). ---
__global__ __launch_bounds__(256) void k_zred(const float* __restrict__ pZ,
    const float* __restrict__ a02, float* __restrict__ sc2g) {
  const int t = blockIdx.x * 256 + threadIdx.x;
  float Z = 0.f;
  for (int s = 0; s < NS1; ++s) Z += pZ[s * T + t];
  sc2g[t] = a02[t] - (flog2(Z) - 80.0f);
}

// --- pass 2: 2048 uniform blocks (8/CU); wave owns 16 codes, sweeps a
//     1024-row split. Tile-skip: contribute only if max(fb)+cc > -36
//     (dropped mass < N_E*2^-36 rel). Live set ~52 (incl. prefetch). ---
__global__ __launch_bounds__(256, 8) void k_pass2(
    const short* __restrict__ ehl, const short* __restrict__ zhl,
    const float* __restrict__ sc2g,
    float* __restrict__ avg, float* __restrict__ scal) {
  const int bid = blockIdx.x;
  const int tid = threadIdx.x;
  __shared__ float red[256];
  __shared__ float sc2[T / RS2];      // 1024

  const int bx = bid & 255, by = bid >> 8;
  const int tb0 = by * (T / RS2);
  for (int i = tid; i < T / RS2; i += 256) sc2[i] = sc2g[tb0 + i];
  __syncthreads();

  const int lane = tid & 63, wv = tid >> 6;
  const int q = lane >> 4, c = lane & 15;
  const int cbase = bx * 64 + wv * 16;
  const int NT = (T / RS2) / 16;     // 64

  const s16x8* eg = (const s16x8*)ehl;
  const int atile = cbase >> 4;
  s16x8 ah = eg[atile * 128 + lane], al = eg[atile * 128 + 64 + lane];

  f32x4 sg;                           // ses2 ~ const (consistent with pass1)
#pragma unroll
  for (int r = 0; r < 4; ++r) sg[r] = NS2F;

  float accP[4], accE[4];
#pragma unroll
  for (int k = 0; k < 4; ++k) { accP[k] = 0.f; accE[k] = 0.f; }

  const s16x8* zt = (const s16x8*)zhl + (size_t)(tb0 >> 4) * 128;
  s16x8 bh = zt[lane], bl = zt[64 + lane];
  float cc = sc2[c];

  for (int tile = 0; tile < NT; ++tile) {
    const int nx = (tile + 1 < NT) ? tile + 1 : tile;
    s16x8 nh = zt[nx * 128 + lane], nl = zt[nx * 128 + 64 + lane];  // prefetch
    float ncc = sc2[nx * 16 + c];

    f32x4 acc = __builtin_amdgcn_mfma_f32_16x16x32_bf16(ah, bh, sg, 0, 0, 0);
    acc = __builtin_amdgcn_mfma_f32_16x16x32_bf16(al, bh, acc, 0, 0, 0);
    acc = __builtin_amdgcn_mfma_f32_16x16x32_bf16(ah, bl, acc, 0, 0, 0);

    // tile-skip: per-lane max over this lane's 4 elements (all share column
    // c -> same cc); wave-uniform branch.
    float m4 = fmaxf(fmaxf(acc[0], acc[1]), fmaxf(acc[2], acc[3]));
    if (__any(m4 + cc > SKIPM)) {
#pragma unroll
      for (int r = 0; r < 4; ++r) {
        float dl = acc[r] + cc;       // fb - lse2 (<=0)
        float p = fexp2(dl);          // underflow -> 0
        accP[r] += p;
        accE[r] = fmaf(p, dl, accE[r]);
      }
    }
    bh = nh; bl = nl; cc = ncc;
  }

  float etot = 0.f;
#pragma unroll
  for (int k = 0; k < 4; ++k) etot += accE[k];

#pragma unroll
  for (int d = 1; d < 16; d <<= 1) {
#pragma unroll
    for (int k = 0; k < 4; ++k) accP[k] += __shfl_xor(accP[k], d);
  }
#pragma unroll
  for (int k = 0; k < 4; ++k) {
    if (c == k) {
      atomicAdd(&avg[cbase + q * 4 + k], accP[k]);
    }
  }
  red[tid] = etot;
  __syncthreads();
  for (int st = 128; st > 0; st >>= 1) {
    if (tid < st) red[tid] += red[tid + st];
    __syncthreads();
  }
  if (tid == 0) atomicAdd(&scal[0], red[0]);
}

// --- merge-final: 32 blocks, thread = row. Top-2 combine (no Z needed),
//     exact fp32 refine, vq sum + straight-through output. Last finished
//     block computes the final scalars (counter on scal[2], 32 fences). ---
__global__ __launch_bounds__(256) void k_mf(
    const float* __restrict__ pm1, const float* __restrict__ pm2,
    const int* __restrict__ pi1, const int* __restrict__ pi2,
    const float* __restrict__ zf, const float* __restrict__ embn,
    const float* __restrict__ ses2, const float* __restrict__ a02,
    float* __restrict__ avg, float* __restrict__ scal, float* __restrict__ out) {
  const int tid = threadIdx.x;
  const int t = blockIdx.x * 256 + tid;
  __shared__ float red[256];
  __shared__ unsigned sord;

  float m1 = -1e30f, m2 = -1e30f;
  int i1 = 0, i2 = 0;
  for (int s = 0; s < NS1; ++s) {
    const int p = s * T + t;
    float sm1 = pm1[p], sm2 = pm2[p];
    int si1 = pi1[p], si2 = pi2[p];
    bool c1 = sm1 > m1;
    float lm = c1 ? m1 : sm1;
    int li = c1 ? i1 : si1;
    float nm1 = c1 ? sm1 : m1;
    int ni1 = c1 ? si1 : i1;
    bool cb = sm2 > m2;
    float mm2 = cb ? sm2 : m2;
    int mi2 = cb ? si2 : i2;
    bool c3 = mm2 > lm;
    m1 = nm1; i1 = ni1;
    m2 = c3 ? mm2 : lm;
    i2 = c3 ? mi2 : li;
  }
  const float a02t = a02[t];

  const float4* zr4 = (const float4*)(zf + (size_t)t * ED);
  float4 z0 = zr4[0], z1 = zr4[1], z2 = zr4[2], z3 = zr4[3];
  float4 z4 = zr4[4], z5 = zr4[5], z6 = zr4[6], z7 = zr4[7];
  float d1 = dot32x(embn + (size_t)i1 * ED, z0, z1, z2, z3, z4, z5, z6, z7);
  float d2 = dot32x(embn + (size_t)i2 * ED, z0, z1, z2, z3, z4, z5, z6, z7);
  float fb1 = fmaf(K2, d1, a02t + ses2[i1]);   // true ses2: exact rule
  float fb2 = fmaf(K2, d2, a02t + ses2[i2]);
  int bi = (fb2 > fb1 || (fb2 == fb1 && i2 < i1)) ? i2 : i1;

  const int b = t >> 8, hw = t & 255;
  float* ob = out + (size_t)b * (ED * 256) + hw;
  float ss = 0.f;
  const float4* e4 = (const float4*)(embn + (size_t)bi * ED);
#pragma unroll
  for (int j = 0; j < 8; ++j) {
    float4 qv = e4[j];
    float4 zv = (j == 0) ? z0 : (j == 1) ? z1 : (j == 2) ? z2 : (j == 3) ? z3
              : (j == 4) ? z4 : (j == 5) ? z5 : (j == 6) ? z6 : z7;
    float df;
    df = qv.x - zv.x; ss = fmaf(df, df, ss); ob[(4 * j + 0) * 256] = zv.x + (qv.x - zv.x);
    df = qv.y - zv.y; ss = fmaf(df, df, ss); ob[(4 * j + 1) * 256] = zv.y + (qv.y - zv.y);
    df = qv.z - zv.z; ss = fmaf(df, df, ss); ob[(4 * j + 2) * 256] = zv.z + (qv.z - zv.z);
    df = qv.w - zv.w; ss = fmaf(df, df, ss); ob[(4 * j + 3) * 256] = zv.w + (qv.w - zv.w);
  }
  red[tid] = ss;
  __syncthreads();
  for (int st = 128; st > 0; st >>= 1) {
    if (tid < st) red[tid] += red[tid + st];
    __syncthreads();
  }
  if (tid == 0) atomicAdd(&scal[1], red[0]);

  // last-block final (avg/scal[0] were completed by the previous kernel)
  __threadfence();
  __syncthreads();
  if (tid == 0) sord = atomicAdd((unsigned*)&scal[2], 1u);
  __syncthreads();
  if (sord == 31) {
    float s = 0.f;
    for (int i = tid; i < N_E; i += 256) {
      float a = avg[i] * (1.0f / T);
      s += a * (flog2(a + 1e-5f) * LN2);
    }
    red[tid] = s;
    __syncthreads();
    for (int st = 128; st > 0; st >>= 1) {
      if (tid < st) red[tid] += red[tid + st];
      __syncthreads();
    }
    if (tid == 0) {
      float avg_entropy = -red[0];
      float se = scal[0];
      float vqs = __hip_atomic_load(&scal[1], __ATOMIC_RELAXED,
                                    __HIP_MEMORY_SCOPE_AGENT);
      float sample_entropy = -(se * LN2) * (1.0f / T);
      float vq = vqs * (1.0f / (T * ED));
      out[T * ED + 0] = vq;
      out[T * ED + 1] = 0.25f * vq;
      out[T * ED + 2] = 0.1f * (sample_entropy - avg_entropy);
    }
  }
}

extern "C" void kernel_launch(void* const* d_in, const int* in_sizes, int n_in,
                              void* d_out, int out_size, void* d_ws, size_t ws_size,
                              hipStream_t stream) {
  const float* z = (const float*)d_in[0];
  const float* emb = (const float*)d_in[1];
  float* out = (float*)d_out;
  float* w = (float*)d_ws;

  float* embn = w;                          // 524288 f
  float* ses2 = embn + 524288;              // 16384
  float* zf   = ses2 + 16384;               // 262144
  float* a02  = zf + 262144;                // 8192
  short* ehl  = (short*)(a02 + 8192);       // 1048576 sh (524288 f)
  short* zhl  = ehl + 1048576;              // 524288 sh  (262144 f)
  float* pm1  = (float*)(zhl + 524288);     // NS1*T = 131072 f
  float* pm2  = pm1 + NS1 * T;              // 131072
  float* pZ   = pm2 + NS1 * T;              // 131072
  int*   pi1  = (int*)(pZ + NS1 * T);       // 131072
  int*   pi2  = pi1 + NS1 * T;              // 131072
  float* avg  = (float*)(pi2 + NS1 * T);    // 16384
  float* scal = avg + 16384;                // 4: sampE, vq, counter, pad
  float* sc2g = scal + 4;                   // 8192

  k_prep<<<161, 256, 0, stream>>>(emb, z, embn, ses2, zf, a02, ehl, zhl,
                                  avg, scal);
  k_pass1<<<dim3(T / 64, NS1), 256, 0, stream>>>(ehl, zhl, a02,
                                                 pm1, pm2, pZ, pi1, pi2);
  k_zred<<<T / 256, 256, 0, stream>>>(pZ, a02, sc2g);
  k_pass2<<<256 * RS2, 256, 0, stream>>>(ehl, zhl, sc2g, avg, scal);
  k_mf<<<32, 256, 0, stream>>>(pm1, pm2, pi1, pi2, zf, embn, ses2, a02,
                               avg, scal, out);
}

// Round 5
// 183.331 us; speedup vs baseline: 1.0788x; 1.0769x over previous
//
#include <hip/hip_runtime.h>

// VQ-VAE vector quantize + losses, MI355X.
// T=8192 rows, N_E=16384 codes, D=32.
// R20: R15-R19 synthesis — per-SIMD issue work ~30K cyc but wall ~140K cyc
//      in every variant; stalls insensitive to occupancy (28->58%) and to
//      register prefetch (compiler rolled it back twice, VGPR=28 proves it).
//      Little's law: 16 waves/CU x 2KB in flight = 32KB -> ~30B/cyc/CU
//      delivered at ~1100cyc loaded latency. Fix = more bytes in flight,
//      decoupled from the register allocator: global_load_lds staging into
//      2x8KB LDS double-buffer, 1 barrier/phase (guide T3-minimum; barrier
//      drains vmcnt -> gload can't be sunk). 4 waves share each staged
//      tile from LDS instead of 4x redundant L1 traffic. 8 blocks/CU x
//      8KB = 64KB in flight/CU. Both sweeps restructured; sc2 staged.
//      Tripwires: WRITE_SIZE ~2.5MB (spill), absmax (gload addressing).

#define N_E 16384
#define ED 32
#define T 8192
#define NS1 16      // pass-1 code splits (1024 codes each)
#define RS2 8       // pass-2 row splits  (1024 rows each)
#define SKIPM -36.0f
#define PHT 4       // tiles per staged phase (8KB)

#define K2 288.53900817779268f    // 200 * log2(e)
#define NS2F -144.26950408889634f // -100 * log2(e)
#define LN2 0.6931471805599453f

typedef __attribute__((ext_vector_type(8))) short s16x8;
typedef __attribute__((ext_vector_type(4))) float f32x4;

__device__ __forceinline__ float fexp2(float x) { return __builtin_amdgcn_exp2f(x); }
__device__ __forceinline__ float flog2(float x) { return __builtin_amdgcn_logf(x); }
__device__ __forceinline__ float fmed3(float a, float b, float c) {
  return __builtin_amdgcn_fmed3f(a, b, c);
}

// async global->LDS, 16B per lane; LDS dest = wave-uniform base + lane*16.
__device__ __forceinline__ void gload16(const void* g, void* l) {
  __builtin_amdgcn_global_load_lds(
      (const __attribute__((address_space(1))) void*)g,
      (__attribute__((address_space(3))) void*)l, 16, 0, 0);
}

__device__ __forceinline__ unsigned short f2bf(float x) {
  unsigned u = __float_as_uint(x);
  unsigned r = (u + 0x7FFFu + ((u >> 16) & 1u)) >> 16;
  return (unsigned short)r;
}
__device__ __forceinline__ float bf2f(unsigned short h) {
  return __uint_as_float(((unsigned)h) << 16);
}

// exact fp32 dot of a streamed row with 8 resident float4s (by value)
__device__ __forceinline__ float dot32x(const float* __restrict__ p,
    float4 z0, float4 z1, float4 z2, float4 z3,
    float4 z4, float4 z5, float4 z6, float4 z7) {
  const float4* e = (const float4*)p;
  float a0 = 0.f, a1 = 0.f, a2 = 0.f, a3 = 0.f; float4 q;
  q = e[0]; a0 = fmaf(q.x, z0.x, a0); a0 = fmaf(q.y, z0.y, a0);
            a0 = fmaf(q.z, z0.z, a0); a0 = fmaf(q.w, z0.w, a0);
  q = e[1]; a1 = fmaf(q.x, z1.x, a1); a1 = fmaf(q.y, z1.y, a1);
            a1 = fmaf(q.z, z1.z, a1); a1 = fmaf(q.w, z1.w, a1);
  q = e[2]; a2 = fmaf(q.x, z2.x, a2); a2 = fmaf(q.y, z2.y, a2);
            a2 = fmaf(q.z, z2.z, a2); a2 = fmaf(q.w, z2.w, a2);
  q = e[3]; a3 = fmaf(q.x, z3.x, a3); a3 = fmaf(q.y, z3.y, a3);
            a3 = fmaf(q.z, z3.z, a3); a3 = fmaf(q.w, z3.w, a3);
  q = e[4]; a0 = fmaf(q.x, z4.x, a0); a0 = fmaf(q.y, z4.y, a0);
            a0 = fmaf(q.z, z4.z, a0); a0 = fmaf(q.w, z4.w, a0);
  q = e[5]; a1 = fmaf(q.x, z5.x, a1); a1 = fmaf(q.y, z5.y, a1);
            a1 = fmaf(q.z, z5.z, a1); a1 = fmaf(q.w, z5.w, a1);
  q = e[6]; a2 = fmaf(q.x, z6.x, a2); a2 = fmaf(q.y, z6.y, a2);
            a2 = fmaf(q.z, z6.z, a2); a2 = fmaf(q.w, z6.w, a2);
  q = e[7]; a3 = fmaf(q.x, z7.x, a3); a3 = fmaf(q.y, z7.y, a3);
            a3 = fmaf(q.z, z7.z, a3); a3 = fmaf(q.w, z7.w, a3);
  return (a0 + a1) + (a2 + a3);
}

// split 8 floats (scaled by sc) of row `row`, group g into hi/lo bf16 frags,
// stored TILE-MAJOR: dst[tile*128 + g*16 + c] (hi), +64 (lo); s16x8 units.
__device__ __forceinline__ void split_store_t(short* __restrict__ base,
    int row, int g, float4 va, float4 vb, float sc) {
  float f[8] = { va.x * sc, va.y * sc, va.z * sc, va.w * sc,
                 vb.x * sc, vb.y * sc, vb.z * sc, vb.w * sc };
  s16x8 H, L;
#pragma unroll
  for (int e = 0; e < 8; ++e) {
    unsigned short h = f2bf(f[e]);
    H[e] = (short)h;
    L[e] = (short)f2bf(f[e] - bf2f(h));
  }
  s16x8* p = (s16x8*)base;
  const int tile = row >> 4, c = row & 15;
  p[tile * 128 + g * 16 + c] = H;
  p[tile * 128 + 64 + g * 16 + c] = L;
}

// --- prep: blocks 0..63 emb rows; 64..95 z transpose; 96..160 zero avg/scal ---
__global__ __launch_bounds__(256) void k_prep(const float* __restrict__ emb,
    const float* __restrict__ z, float* __restrict__ embn,
    float* __restrict__ ses2, float* __restrict__ zf, float* __restrict__ a02,
    short* __restrict__ ehl, short* __restrict__ zhl, float* __restrict__ avg,
    float* __restrict__ scal) {
  if (blockIdx.x < 64) {
    int n = blockIdx.x * 256 + threadIdx.x;
    const float4* r4 = (const float4*)(emb + (size_t)n * ED);
    float4 v[8]; float s = 0.f;
#pragma unroll
    for (int j = 0; j < 8; ++j) {
      v[j] = r4[j];
      s = fmaf(v[j].x, v[j].x, s); s = fmaf(v[j].y, v[j].y, s);
      s = fmaf(v[j].z, v[j].z, s); s = fmaf(v[j].w, v[j].w, s);
    }
    float inv = 1.0f / fmaxf(sqrtf(s), 1e-12f);
    float s2 = 0.f;
    float4* o4 = (float4*)(embn + (size_t)n * ED);
#pragma unroll
    for (int j = 0; j < 8; ++j) {
      float4 w; w.x = v[j].x * inv; w.y = v[j].y * inv;
      w.z = v[j].z * inv; w.w = v[j].w * inv;
      o4[j] = w; v[j] = w;
      s2 = fmaf(w.x, w.x, s2); s2 = fmaf(w.y, w.y, s2);
      s2 = fmaf(w.z, w.z, s2); s2 = fmaf(w.w, w.w, s2);
    }
    ses2[n] = NS2F * s2;               // true value, for the exact refine
#pragma unroll
    for (int g = 0; g < 4; ++g)
      split_store_t(ehl, n, g, v[2 * g], v[2 * g + 1], 1.0f);
  } else if (blockIdx.x < 96) {
    int t = (blockIdx.x - 64) * 256 + threadIdx.x;
    int b = t >> 8, hw = t & 255;
    const float* base = z + (size_t)b * (ED * 256) + hw;
    float4 v[8]; float s = 0.f;
#pragma unroll
    for (int j = 0; j < 8; ++j) {
      float4 w;
      w.x = base[(4 * j + 0) * 256]; w.y = base[(4 * j + 1) * 256];
      w.z = base[(4 * j + 2) * 256]; w.w = base[(4 * j + 3) * 256];
      v[j] = w;
      s = fmaf(w.x, w.x, s); s = fmaf(w.y, w.y, s);
      s = fmaf(w.z, w.z, s); s = fmaf(w.w, w.w, s);
    }
    float inv = 1.0f / fmaxf(sqrtf(s), 1e-12f);
    float s2 = 0.f;
    float4* o4 = (float4*)(zf + (size_t)t * ED);
#pragma unroll
    for (int j = 0; j < 8; ++j) {
      float4 w; w.x = v[j].x * inv; w.y = v[j].y * inv;
      w.z = v[j].z * inv; w.w = v[j].w * inv;
      o4[j] = w; v[j] = w;
      s2 = fmaf(w.x, w.x, s2); s2 = fmaf(w.y, w.y, s2);
      s2 = fmaf(w.z, w.z, s2); s2 = fmaf(w.w, w.w, s2);
    }
    a02[t] = NS2F * s2;
#pragma unroll
    for (int g = 0; g < 4; ++g)
      split_store_t(zhl, t, g, v[2 * g], v[2 * g + 1], K2);
  } else if (blockIdx.x < 160) {
    avg[(blockIdx.x - 96) * 256 + threadIdx.x] = 0.f;
  } else {
    if (threadIdx.x < 4) scal[threadIdx.x] = 0.f;  // [0]=sampE [1]=vq [2]=cnt
  }
}

// --- pass 1: block = 64 rows (4 waves x 16), sweeps a 1024-code split.
//     B-stream staged via global_load_lds into 2x8KB LDS dbuf, 4 tiles
//     per phase, 1 barrier/phase (drains vmcnt). Waves read tiles from
//     LDS (shared across 4 waves). Top-2 via mantissa-packed keys. ---
__global__ __launch_bounds__(256, 8) void k_pass1(
    const short* __restrict__ ehl, const short* __restrict__ zhl,
    const float* __restrict__ a02, float* __restrict__ pm1,
    float* __restrict__ pm2, float* __restrict__ pZ,
    int* __restrict__ pi1, int* __restrict__ pi2) {
  const int tid = threadIdx.x;
  const int lane = tid & 63, wv = tid >> 6;
  const int q = lane >> 4, c = lane & 15;
  const int rowbase = blockIdx.x * 64 + wv * 16;
  const int nb0 = blockIdx.y * (N_E / NS1);
  const int NT = (N_E / NS1) / 16;  // 64
  const int NP = NT / PHT;          // 16

  __shared__ s16x8 dbuf[2][PHT * 128];   // 2 x 8KB

  const s16x8* zg = (const s16x8*)zhl;
  const int atile = rowbase >> 4;
  s16x8 ah = zg[atile * 128 + lane], al = zg[atile * 128 + 64 + lane];

  f32x4 bias;
#pragma unroll
  for (int r = 0; r < 4; ++r)
    bias[r] = a02[rowbase + q * 4 + r] + (80.0f + NS2F);

  float m1[4], m2[4], Zs[4];
#pragma unroll
  for (int k = 0; k < 4; ++k) { m1[k] = -1e30f; m2[k] = -1e30f; Zs[k] = 0.f; }

  const s16x8* eg = (const s16x8*)ehl + (size_t)(nb0 >> 4) * 128;

  // stage phase 0 (each wave covers 2KB: 2 x 1KB calls)
  gload16(eg + wv * 128 + lane,      &dbuf[0][wv * 128]);
  gload16(eg + wv * 128 + 64 + lane, &dbuf[0][wv * 128 + 64]);
  __syncthreads();

  for (int p = 0; p < NP; ++p) {
    if (p + 1 < NP) {
      const s16x8* gs = eg + (p + 1) * (PHT * 128);
      s16x8* lb = &dbuf[(p + 1) & 1][0];
      gload16(gs + wv * 128 + lane,      lb + wv * 128);
      gload16(gs + wv * 128 + 64 + lane, lb + wv * 128 + 64);
    }
    const s16x8* bb = &dbuf[p & 1][0];
#pragma unroll
    for (int tt = 0; tt < PHT; ++tt) {
      s16x8 bh = bb[tt * 128 + lane], bl = bb[tt * 128 + 64 + lane];

      f32x4 acc = __builtin_amdgcn_mfma_f32_16x16x32_bf16(ah, bh, bias, 0, 0, 0);
      acc = __builtin_amdgcn_mfma_f32_16x16x32_bf16(al, bh, acc, 0, 0, 0);
      acc = __builtin_amdgcn_mfma_f32_16x16x32_bf16(ah, bl, acc, 0, 0, 0);

      const unsigned tu = (unsigned)(p * PHT + tt);       // uniform 6-bit idx
#pragma unroll
      for (int r = 0; r < 4; ++r) {
        float fb = acc[r];
        float key = __uint_as_float((__float_as_uint(fb) & 0xFFFFFFC0u) | tu);
        m2[r] = fmed3(key, m1[r], m2[r]);   // 2nd-max of {key,m1,m2}
        m1[r] = fmaxf(m1[r], key);
        Zs[r] += fexp2(fb);
      }
    }
    __syncthreads();   // drains vmcnt: phase p+1 staged; all reads of buf done
  }

  // decode indices from this lane's own keys (c local), then reduce
  int i1[4], i2[4];
#pragma unroll
  for (int k = 0; k < 4; ++k) {
    i1[k] = nb0 + (int)((__float_as_uint(m1[k]) & 63u) << 4) + c;
    i2[k] = nb0 + (int)((__float_as_uint(m2[k]) & 63u) << 4) + c;
  }

#pragma unroll
  for (int d = 1; d < 16; d <<= 1) {
#pragma unroll
    for (int k = 0; k < 4; ++k) {
      float om1 = __shfl_xor(m1[k], d);
      float om2 = __shfl_xor(m2[k], d);
      float oZ = __shfl_xor(Zs[k], d);
      int oi1 = __shfl_xor(i1[k], d);
      int oi2 = __shfl_xor(i2[k], d);
      bool c1 = om1 > m1[k];
      float lm = c1 ? m1[k] : om1;
      int li = c1 ? i1[k] : oi1;
      float nm1 = c1 ? om1 : m1[k];
      int ni1 = c1 ? oi1 : i1[k];
      bool cb = om2 > m2[k];
      float mm2 = cb ? om2 : m2[k];
      int mi2 = cb ? oi2 : i2[k];
      bool c3 = mm2 > lm;
      m1[k] = nm1; i1[k] = ni1;
      m2[k] = c3 ? mm2 : lm;
      i2[k] = c3 ? mi2 : li;
      Zs[k] += oZ;
    }
  }

#pragma unroll
  for (int k = 0; k < 4; ++k) {
    if (c == k) {
      const int t = rowbase + q * 4 + k;
      const int p = blockIdx.y * T + t;
      pm1[p] = m1[k]; pm2[p] = m2[k]; pZ[p] = Zs[k];
      pi1[p] = i1[k]; pi2[p] = i2[k];
    }
  }
}

// --- zred: per-row Z merge + lse shift, once. ---
__global__ __launch_bounds__(256) void k_zred(const float* __restrict__ pZ,
    const float* __restrict__ a02, float* __restrict__ sc2g) {
  const int t = blockIdx.x * 256 + threadIdx.x;
  float Z = 0.f;
  for (int s = 0; s < NS1; ++s) Z += pZ[s * T + t];
  sc2g[t] = a02[t] - (flog2(Z) - 80.0f);
}

// --- pass 2: block = 64 codes (4 waves x 16), sweeps a 1024-row split.
//     zhl stream staged via global_load_lds (2x8KB dbuf), sc2 split staged
//     once (4KB). Tile-skip on max(fb)+cc > -36. LDS 20KB -> 8 blocks/CU. ---
__global__ __launch_bounds__(256, 8) void k_pass2(
    const short* __restrict__ ehl, const short* __restrict__ zhl,
    const float* __restrict__ sc2g,
    float* __restrict__ avg, float* __restrict__ scal) {
  const int tid = threadIdx.x;
  const int lane = tid & 63, wv = tid >> 6;
  const int q = lane >> 4, c = lane & 15;
  const int bx = blockIdx.x & 255, by = blockIdx.x >> 8;
  const int tb0 = by * (T / RS2);
  const int cbase = bx * 64 + wv * 16;
  const int NT = (T / RS2) / 16;    // 64
  const int NP = NT / PHT;          // 16

  __shared__ s16x8 dbuf[2][PHT * 128];   // 16KB
  __shared__ float sc2l[T / RS2];        // 4KB

  // stage sc2 split (1024 floats, 4 per thread)
  ((float4*)sc2l)[tid] = ((const float4*)(sc2g + tb0))[tid];

  const s16x8* eg = (const s16x8*)ehl;
  const int atile = cbase >> 4;
  s16x8 ah = eg[atile * 128 + lane], al = eg[atile * 128 + 64 + lane];

  f32x4 sg;                           // ses2 ~ const (consistent with pass1)
#pragma unroll
  for (int r = 0; r < 4; ++r) sg[r] = NS2F;

  float accP[4], accE[4];
#pragma unroll
  for (int k = 0; k < 4; ++k) { accP[k] = 0.f; accE[k] = 0.f; }

  const s16x8* zt = (const s16x8*)zhl + (size_t)(tb0 >> 4) * 128;

  gload16(zt + wv * 128 + lane,      &dbuf[0][wv * 128]);
  gload16(zt + wv * 128 + 64 + lane, &dbuf[0][wv * 128 + 64]);
  __syncthreads();

  for (int p = 0; p < NP; ++p) {
    if (p + 1 < NP) {
      const s16x8* gs = zt + (p + 1) * (PHT * 128);
      s16x8* lb = &dbuf[(p + 1) & 1][0];
      gload16(gs + wv * 128 + lane,      lb + wv * 128);
      gload16(gs + wv * 128 + 64 + lane, lb + wv * 128 + 64);
    }
    const s16x8* bb = &dbuf[p & 1][0];
#pragma unroll
    for (int tt = 0; tt < PHT; ++tt) {
      s16x8 bh = bb[tt * 128 + lane], bl = bb[tt * 128 + 64 + lane];
      float cc = sc2l[(p * PHT + tt) * 16 + c];

      f32x4 acc = __builtin_amdgcn_mfma_f32_16x16x32_bf16(ah, bh, sg, 0, 0, 0);
      acc = __builtin_amdgcn_mfma_f32_16x16x32_bf16(al, bh, acc, 0, 0, 0);
      acc = __builtin_amdgcn_mfma_f32_16x16x32_bf16(ah, bl, acc, 0, 0, 0);

      float m4 = fmaxf(fmaxf(acc[0], acc[1]), fmaxf(acc[2], acc[3]));
      if (__any(m4 + cc > SKIPM)) {
#pragma unroll
        for (int r = 0; r < 4; ++r) {
          float dl = acc[r] + cc;     // fb - lse2 (<=0)
          float p2 = fexp2(dl);       // underflow -> 0
          accP[r] += p2;
          accE[r] = fmaf(p2, dl, accE[r]);
        }
      }
    }
    __syncthreads();
  }

  float etot = 0.f;
#pragma unroll
  for (int k = 0; k < 4; ++k) etot += accE[k];

#pragma unroll
  for (int d = 1; d < 16; d <<= 1) {
#pragma unroll
    for (int k = 0; k < 4; ++k) accP[k] += __shfl_xor(accP[k], d);
  }
#pragma unroll
  for (int k = 0; k < 4; ++k) {
    if (c == k) {
      atomicAdd(&avg[cbase + q * 4 + k], accP[k]);
    }
  }
  float* red = sc2l;                 // sweep done; reuse LDS
  red[tid] = etot;
  __syncthreads();
  for (int st = 128; st > 0; st >>= 1) {
    if (tid < st) red[tid] += red[tid + st];
    __syncthreads();
  }
  if (tid == 0) atomicAdd(&scal[0], red[0]);
}

// --- merge-final: 32 blocks, thread = row. Top-2 combine, exact fp32
//     refine, vq sum + straight-through output; last block finals. ---
__global__ __launch_bounds__(256) void k_mf(
    const float* __restrict__ pm1, const float* __restrict__ pm2,
    const int* __restrict__ pi1, const int* __restrict__ pi2,
    const float* __restrict__ zf, const float* __restrict__ embn,
    const float* __restrict__ ses2, const float* __restrict__ a02,
    float* __restrict__ avg, float* __restrict__ scal, float* __restrict__ out) {
  const int tid = threadIdx.x;
  const int t = blockIdx.x * 256 + tid;
  __shared__ float red[256];
  __shared__ unsigned sord;

  float m1 = -1e30f, m2 = -1e30f;
  int i1 = 0, i2 = 0;
  for (int s = 0; s < NS1; ++s) {
    const int p = s * T + t;
    float sm1 = pm1[p], sm2 = pm2[p];
    int si1 = pi1[p], si2 = pi2[p];
    bool c1 = sm1 > m1;
    float lm = c1 ? m1 : sm1;
    int li = c1 ? i1 : si1;
    float nm1 = c1 ? sm1 : m1;
    int ni1 = c1 ? si1 : i1;
    bool cb = sm2 > m2;
    float mm2 = cb ? sm2 : m2;
    int mi2 = cb ? si2 : i2;
    bool c3 = mm2 > lm;
    m1 = nm1; i1 = ni1;
    m2 = c3 ? mm2 : lm;
    i2 = c3 ? mi2 : li;
  }
  const float a02t = a02[t];

  const float4* zr4 = (const float4*)(zf + (size_t)t * ED);
  float4 z0 = zr4[0], z1 = zr4[1], z2 = zr4[2], z3 = zr4[3];
  float4 z4 = zr4[4], z5 = zr4[5], z6 = zr4[6], z7 = zr4[7];
  float d1 = dot32x(embn + (size_t)i1 * ED, z0, z1, z2, z3, z4, z5, z6, z7);
  float d2 = dot32x(embn + (size_t)i2 * ED, z0, z1, z2, z3, z4, z5, z6, z7);
  float fb1 = fmaf(K2, d1, a02t + ses2[i1]);   // true ses2: exact rule
  float fb2 = fmaf(K2, d2, a02t + ses2[i2]);
  int bi = (fb2 > fb1 || (fb2 == fb1 && i2 < i1)) ? i2 : i1;

  const int b = t >> 8, hw = t & 255;
  float* ob = out + (size_t)b * (ED * 256) + hw;
  float ss = 0.f;
  const float4* e4 = (const float4*)(embn + (size_t)bi * ED);
#pragma unroll
  for (int j = 0; j < 8; ++j) {
    float4 qv = e4[j];
    float4 zv = (j == 0) ? z0 : (j == 1) ? z1 : (j == 2) ? z2 : (j == 3) ? z3
              : (j == 4) ? z4 : (j == 5) ? z5 : (j == 6) ? z6 : z7;
    float df;
    df = qv.x - zv.x; ss = fmaf(df, df, ss); ob[(4 * j + 0) * 256] = zv.x + (qv.x - zv.x);
    df = qv.y - zv.y; ss = fmaf(df, df, ss); ob[(4 * j + 1) * 256] = zv.y + (qv.y - zv.y);
    df = qv.z - zv.z; ss = fmaf(df, df, ss); ob[(4 * j + 2) * 256] = zv.z + (qv.z - zv.z);
    df = qv.w - zv.w; ss = fmaf(df, df, ss); ob[(4 * j + 3) * 256] = zv.w + (qv.w - zv.w);
  }
  red[tid] = ss;
  __syncthreads();
  for (int st = 128; st > 0; st >>= 1) {
    if (tid < st) red[tid] += red[tid + st];
    __syncthreads();
  }
  if (tid == 0) atomicAdd(&scal[1], red[0]);

  // last-block final (avg/scal[0] were completed by the previous kernel)
  __threadfence();
  __syncthreads();
  if (tid == 0) sord = atomicAdd((unsigned*)&scal[2], 1u);
  __syncthreads();
  if (sord == 31) {
    float s = 0.f;
    for (int i = tid; i < N_E; i += 256) {
      float a = avg[i] * (1.0f / T);
      s += a * (flog2(a + 1e-5f) * LN2);
    }
    red[tid] = s;
    __syncthreads();
    for (int st = 128; st > 0; st >>= 1) {
      if (tid < st) red[tid] += red[tid + st];
      __syncthreads();
    }
    if (tid == 0) {
      float avg_entropy = -red[0];
      float se = scal[0];
      float vqs = __hip_atomic_load(&scal[1], __ATOMIC_RELAXED,
                                    __HIP_MEMORY_SCOPE_AGENT);
      float sample_entropy = -(se * LN2) * (1.0f / T);
      float vq = vqs * (1.0f / (T * ED));
      out[T * ED + 0] = vq;
      out[T * ED + 1] = 0.25f * vq;
      out[T * ED + 2] = 0.1f * (sample_entropy - avg_entropy);
    }
  }
}

extern "C" void kernel_launch(void* const* d_in, const int* in_sizes, int n_in,
                              void* d_out, int out_size, void* d_ws, size_t ws_size,
                              hipStream_t stream) {
  const float* z = (const float*)d_in[0];
  const float* emb = (const float*)d_in[1];
  float* out = (float*)d_out;
  float* w = (float*)d_ws;

  float* embn = w;                          // 524288 f
  float* ses2 = embn + 524288;              // 16384
  float* zf   = ses2 + 16384;               // 262144
  float* a02  = zf + 262144;                // 8192
  short* ehl  = (short*)(a02 + 8192);       // 1048576 sh (524288 f)
  short* zhl  = ehl + 1048576;              // 524288 sh  (262144 f)
  float* pm1  = (float*)(zhl + 524288);     // NS1*T = 131072 f
  float* pm2  = pm1 + NS1 * T;              // 131072
  float* pZ   = pm2 + NS1 * T;              // 131072
  int*   pi1  = (int*)(pZ + NS1 * T);       // 131072
  int*   pi2  = pi1 + NS1 * T;              // 131072
  float* avg  = (float*)(pi2 + NS1 * T);    // 16384
  float* scal = avg + 16384;                // 4: sampE, vq, counter, pad
  float* sc2g = scal + 4;                   // 8192

  k_prep<<<161, 256, 0, stream>>>(emb, z, embn, ses2, zf, a02, ehl, zhl,
                                  avg, scal);
  k_pass1<<<dim3(T / 64, NS1), 256, 0, stream>>>(ehl, zhl, a02,
                                                 pm1, pm2, pZ, pi1, pi2);
  k_zred<<<T / 256, 256, 0, stream>>>(pZ, a02, sc2g);
  k_pass2<<<256 * RS2, 256, 0, stream>>>(ehl, zhl, sc2g, avg, scal);
  k_mf<<<32, 256, 0, stream>>>(pm1, pm2, pi1, pi2, zf, embn, ses2, a02,
                               avg, scal, out);
}